// Round 1
// baseline (942.257 us; speedup 1.0000x reference)
//
#include <hip/hip_runtime.h>
#include <hip/hip_bf16.h>

#define B_  32
#define R_  256
#define T_  512
#define C_  16
#define C1_ 64
#define C2_ 128

// ---------- bf16 helpers (store y/Z as raw ushort, RNE rounding) ----------
__device__ __forceinline__ unsigned short f2bf(float f) {
    unsigned u = __float_as_uint(f);
    return (unsigned short)((u + 0x7fffu + ((u >> 16) & 1u)) >> 16);
}
__device__ __forceinline__ float bf2f_lo(unsigned w) { return __uint_as_float(w << 16); }
__device__ __forceinline__ float bf2f_hi(unsigned w) { return __uint_as_float(w & 0xffff0000u); }

// =====================================================================
// K1: x[B,R,T,C] fp32 -> y[B,C,R,T] bf16, rows centered & L2-normalized.
// One block per (b,r). Reads 32KB contiguous, stats per c, writes 16 rows.
// =====================================================================
__global__ __launch_bounds__(256) void k1_normalize(const float* __restrict__ x,
                                                    unsigned short* __restrict__ y) {
    const int r = blockIdx.x, b = blockIdx.y, tid = threadIdx.x;
    __shared__ float xs[T_ * C_];          // 32 KB
    __shared__ float psum[16][17], psq[16][17];
    __shared__ float s_mean[16], s_inv[16];

    const float4* src = reinterpret_cast<const float4*>(x + ((size_t)(b * R_ + r)) * T_ * C_);
    float4* dst = reinterpret_cast<float4*>(xs);
#pragma unroll
    for (int j = 0; j < 8; ++j) dst[tid + j * 256] = src[tid + j * 256];
    __syncthreads();

    {   // per-c partial stats: 16 segments of 32 t each
        const int c = tid & 15, seg = tid >> 4;
        float s = 0.f, q = 0.f;
#pragma unroll
        for (int i = 0; i < 32; ++i) {
            float v = xs[(seg * 32 + i) * C_ + c];
            s += v; q += v * v;
        }
        psum[seg][c] = s; psq[seg][c] = q;
    }
    __syncthreads();
    if (tid < 16) {
        float S = 0.f, Q = 0.f;
#pragma unroll
        for (int g = 0; g < 16; ++g) { S += psum[g][tid]; Q += psq[g][tid]; }
        float mean = S * (1.f / T_);
        float nrm2 = Q - S * mean;         // sum((x-mean)^2) = Q - S^2/T
        s_mean[tid] = mean;
        s_inv[tid] = rsqrtf(nrm2);
    }
    __syncthreads();

    const int cc = tid >> 4, l = tid & 15;
    const float mean = s_mean[cc], inv = s_inv[cc];
    unsigned* out = reinterpret_cast<unsigned*>(y + (((size_t)(b * C_ + cc)) * R_ + r) * T_);
#pragma unroll
    for (int j = 0; j < 16; ++j) {
        const int t = j * 32 + l * 2;      // even; lanes in a c-group write contiguous
        float v0 = (xs[t * C_ + cc] - mean) * inv;
        float v1 = (xs[(t + 1) * C_ + cc] - mean) * inv;
        out[t >> 1] = (unsigned)f2bf(v0) | ((unsigned)f2bf(v1) << 16);
    }
}

// =====================================================================
// K2: Z[b,o,c,t] = sum_k W_edge[o,c,k] * y[b,c,k,t]   (bf16 out)
// Per-block: (b, c, t-chunk of 128); GEMM M=64(o) N=128(t) K=256.
// =====================================================================
__global__ __launch_bounds__(256) void k2_edgeproj(const float* __restrict__ W_edge,
                                                   const unsigned short* __restrict__ y,
                                                   unsigned short* __restrict__ Z) {
    const int t0 = blockIdx.x * 128;
    const int c = blockIdx.y;
    const int b = blockIdx.z;
    const int tid = threadIdx.x;

    __shared__ float As[64][36];    // [o][kk], pad 36 keeps float4 align + 2-way banks
    __shared__ float Bs[32][132];   // [kk][tt]

    float acc[4][8];
#pragma unroll
    for (int i = 0; i < 4; ++i)
#pragma unroll
        for (int j = 0; j < 8; ++j) acc[i][j] = 0.f;

    const int ty = tid >> 4, tx = tid & 15;          // o = ty*4+i, t = t0 + tx*8 + j
    const int la_o = tid >> 2, la_k = (tid & 3) * 8; // A-load mapping
    const int lb_r = tid >> 3, lb_t = (tid & 7) * 16;// B-load mapping

    for (int k0 = 0; k0 < R_; k0 += 32) {
        // stage A: W_edge[o, c, k0..k0+31]  (64x32 fp32)
        {
            const float* s = W_edge + ((size_t)(la_o * C_ + c)) * R_ + k0 + la_k;
            float4 a0 = *(const float4*)s;
            float4 a1 = *(const float4*)(s + 4);
            *(float4*)&As[la_o][la_k] = a0;
            *(float4*)&As[la_o][la_k + 4] = a1;
        }
        // stage B: y[b, c, k0+row, t0 .. t0+127]  (32x128 bf16 -> fp32)
        {
            const unsigned short* s = y + (((size_t)(b * C_ + c)) * R_ + k0 + lb_r) * T_ + t0 + lb_t;
            uint4 p0 = *(const uint4*)s;
            uint4 p1 = *(const uint4*)(s + 8);
            float f[16];
            f[0]=bf2f_lo(p0.x); f[1]=bf2f_hi(p0.x); f[2]=bf2f_lo(p0.y); f[3]=bf2f_hi(p0.y);
            f[4]=bf2f_lo(p0.z); f[5]=bf2f_hi(p0.z); f[6]=bf2f_lo(p0.w); f[7]=bf2f_hi(p0.w);
            f[8]=bf2f_lo(p1.x); f[9]=bf2f_hi(p1.x); f[10]=bf2f_lo(p1.y); f[11]=bf2f_hi(p1.y);
            f[12]=bf2f_lo(p1.z); f[13]=bf2f_hi(p1.z); f[14]=bf2f_lo(p1.w); f[15]=bf2f_hi(p1.w);
#pragma unroll
            for (int q = 0; q < 4; ++q)
                *(float4*)&Bs[lb_r][lb_t + q * 4] = make_float4(f[q*4], f[q*4+1], f[q*4+2], f[q*4+3]);
        }
        __syncthreads();
#pragma unroll
        for (int kk = 0; kk < 32; ++kk) {
            float a0 = As[ty * 4 + 0][kk];
            float a1 = As[ty * 4 + 1][kk];
            float a2 = As[ty * 4 + 2][kk];
            float a3 = As[ty * 4 + 3][kk];
            float4 b0 = *(float4*)&Bs[kk][tx * 8];
            float4 b1 = *(float4*)&Bs[kk][tx * 8 + 4];
            acc[0][0] += a0*b0.x; acc[0][1] += a0*b0.y; acc[0][2] += a0*b0.z; acc[0][3] += a0*b0.w;
            acc[0][4] += a0*b1.x; acc[0][5] += a0*b1.y; acc[0][6] += a0*b1.z; acc[0][7] += a0*b1.w;
            acc[1][0] += a1*b0.x; acc[1][1] += a1*b0.y; acc[1][2] += a1*b0.z; acc[1][3] += a1*b0.w;
            acc[1][4] += a1*b1.x; acc[1][5] += a1*b1.y; acc[1][6] += a1*b1.z; acc[1][7] += a1*b1.w;
            acc[2][0] += a2*b0.x; acc[2][1] += a2*b0.y; acc[2][2] += a2*b0.z; acc[2][3] += a2*b0.w;
            acc[2][4] += a2*b1.x; acc[2][5] += a2*b1.y; acc[2][6] += a2*b1.z; acc[2][7] += a2*b1.w;
            acc[3][0] += a3*b0.x; acc[3][1] += a3*b0.y; acc[3][2] += a3*b0.z; acc[3][3] += a3*b0.w;
            acc[3][4] += a3*b1.x; acc[3][5] += a3*b1.y; acc[3][6] += a3*b1.z; acc[3][7] += a3*b1.w;
        }
        __syncthreads();
    }

    // store Z bf16: rows o = ty*4+i, t = t0 + tx*8 .. +7
#pragma unroll
    for (int i = 0; i < 4; ++i) {
        const int o = ty * 4 + i;
        unsigned short* d = Z + (((size_t)(b * C1_ + o)) * C_ + c) * T_ + t0 + tx * 8;
        uint4 pk;
        pk.x = (unsigned)f2bf(acc[i][0]) | ((unsigned)f2bf(acc[i][1]) << 16);
        pk.y = (unsigned)f2bf(acc[i][2]) | ((unsigned)f2bf(acc[i][3]) << 16);
        pk.z = (unsigned)f2bf(acc[i][4]) | ((unsigned)f2bf(acc[i][5]) << 16);
        pk.w = (unsigned)f2bf(acc[i][6]) | ((unsigned)f2bf(acc[i][7]) << 16);
        *(uint4*)d = pk;
    }
}

// =====================================================================
// K3: e_part[half,b,r,o] = sum_{c in half} sum_t y[b,c,r,t]*Z[b,o,c,t]
// Block: (r-tile 64, b, c-half). LDS tiles stored t-major (transposed)
// so the inner dot reads both operands as float4.
// =====================================================================
__global__ __launch_bounds__(256) void k3_edge_gemm(const unsigned short* __restrict__ y,
                                                    const unsigned short* __restrict__ Z,
                                                    float* __restrict__ e_part) {
    const int r0 = blockIdx.x * 64;
    const int b = blockIdx.y;
    const int half = blockIdx.z;
    const int c0 = half * 8;
    const int tid = threadIdx.x;

    __shared__ float Ys[64][68];   // [tt][rr]
    __shared__ float Zs[64][68];   // [tt][oo]

    float acc[4][4];
#pragma unroll
    for (int i = 0; i < 4; ++i)
#pragma unroll
        for (int j = 0; j < 4; ++j) acc[i][j] = 0.f;

    const int ty = tid >> 4, tx = tid & 15;     // r = r0+ty*4+i, o = tx*4+j
    const int lrow = tid >> 2;                  // 0..63 (r for Y, o for Z)
    const int lt = (tid & 3) * 16;              // t offset 0..48

    for (int ci = 0; ci < 8; ++ci) {
        const int c = c0 + ci;
        const unsigned short* yb = y + (((size_t)(b * C_ + c)) * R_ + r0 + lrow) * T_;
        const unsigned short* zb = Z + (((size_t)(b * C1_ + lrow)) * C_ + c) * T_;
        for (int tc = 0; tc < 8; ++tc) {
            const int t0 = tc * 64;
            uint4 ya = *(const uint4*)(yb + t0 + lt);
            uint4 yc = *(const uint4*)(yb + t0 + lt + 8);
            uint4 za = *(const uint4*)(zb + t0 + lt);
            uint4 zc = *(const uint4*)(zb + t0 + lt + 8);
            __syncthreads();   // previous compute done before overwriting LDS
            float f[16];
            f[0]=bf2f_lo(ya.x); f[1]=bf2f_hi(ya.x); f[2]=bf2f_lo(ya.y); f[3]=bf2f_hi(ya.y);
            f[4]=bf2f_lo(ya.z); f[5]=bf2f_hi(ya.z); f[6]=bf2f_lo(ya.w); f[7]=bf2f_hi(ya.w);
            f[8]=bf2f_lo(yc.x); f[9]=bf2f_hi(yc.x); f[10]=bf2f_lo(yc.y); f[11]=bf2f_hi(yc.y);
            f[12]=bf2f_lo(yc.z); f[13]=bf2f_hi(yc.z); f[14]=bf2f_lo(yc.w); f[15]=bf2f_hi(yc.w);
#pragma unroll
            for (int i = 0; i < 16; ++i) Ys[lt + i][lrow] = f[i];
            f[0]=bf2f_lo(za.x); f[1]=bf2f_hi(za.x); f[2]=bf2f_lo(za.y); f[3]=bf2f_hi(za.y);
            f[4]=bf2f_lo(za.z); f[5]=bf2f_hi(za.z); f[6]=bf2f_lo(za.w); f[7]=bf2f_hi(za.w);
            f[8]=bf2f_lo(zc.x); f[9]=bf2f_hi(zc.x); f[10]=bf2f_lo(zc.y); f[11]=bf2f_hi(zc.y);
            f[12]=bf2f_lo(zc.z); f[13]=bf2f_hi(zc.z); f[14]=bf2f_lo(zc.w); f[15]=bf2f_hi(zc.w);
#pragma unroll
            for (int i = 0; i < 16; ++i) Zs[lt + i][lrow] = f[i];
            __syncthreads();
#pragma unroll
            for (int tt = 0; tt < 64; ++tt) {
                float4 yv = *(float4*)&Ys[tt][ty * 4];
                float4 zv = *(float4*)&Zs[tt][tx * 4];
                acc[0][0] += yv.x*zv.x; acc[0][1] += yv.x*zv.y; acc[0][2] += yv.x*zv.z; acc[0][3] += yv.x*zv.w;
                acc[1][0] += yv.y*zv.x; acc[1][1] += yv.y*zv.y; acc[1][2] += yv.y*zv.z; acc[1][3] += yv.y*zv.w;
                acc[2][0] += yv.z*zv.x; acc[2][1] += yv.z*zv.y; acc[2][2] += yv.z*zv.z; acc[2][3] += yv.z*zv.w;
                acc[3][0] += yv.w*zv.x; acc[3][1] += yv.w*zv.y; acc[3][2] += yv.w*zv.z; acc[3][3] += yv.w*zv.w;
            }
        }
    }
#pragma unroll
    for (int i = 0; i < 4; ++i) {
        const int r = r0 + ty * 4 + i;
        float* d = e_part + (((size_t)(half * B_ + b)) * R_ + r) * C1_ + tx * 4;
        *(float4*)d = make_float4(acc[i][0], acc[i][1], acc[i][2], acc[i][3]);
    }
}

// K3b: e = leaky_relu(part0 + part1 + b_edge[o])
__global__ __launch_bounds__(256) void k3b_combine(const float* __restrict__ e_part,
                                                   const float* __restrict__ b_edge,
                                                   float* __restrict__ e) {
    const int idx = blockIdx.x * 256 + threadIdx.x;   // < B*R*C1 = 524288
    float v = e_part[idx] + e_part[B_ * R_ * C1_ + idx] + b_edge[idx & 63];
    e[idx] = v >= 0.f ? v : 0.01f * v;
}

// =====================================================================
// K4: attention MLP. One block per b. pooled->h->att(sigmoid)
// =====================================================================
__global__ __launch_bounds__(256) void k4_att(const float* __restrict__ e,
                                              const float* __restrict__ W1, const float* __restrict__ b1,
                                              const float* __restrict__ W2, const float* __restrict__ b2,
                                              float* __restrict__ out_att) {
    const int b = blockIdx.x, tid = threadIdx.x;
    __shared__ float pooled[R_];
    __shared__ float h[64];
    {
        const float4* ev = reinterpret_cast<const float4*>(e + ((size_t)(b * R_ + tid)) * C1_);
        float s = 0.f;
#pragma unroll
        for (int j = 0; j < 16; ++j) { float4 v = ev[j]; s += v.x + v.y + v.z + v.w; }
        pooled[tid] = s * (1.f / 64.f);
    }
    __syncthreads();
    if (tid < 64) {
        float a = b1[tid];
        const float* w = W1 + tid * R_;
        for (int r = 0; r < R_; ++r) a += w[r] * pooled[r];
        h[tid] = fmaxf(a, 0.f);
    }
    __syncthreads();
    {
        float a = b2[tid];
        const float* w = W2 + tid * 64;
#pragma unroll
        for (int j = 0; j < 64; ++j) a += w[j] * h[j];
        out_att[b * R_ + tid] = 1.f / (1.f + __expf(-a));
    }
}

// =====================================================================
// K5: o[b,oc] = leaky(sum_{c1,r} att[b,r]*e[b,r,c1]*W_node[oc,c1,r] + b_node[oc])
// =====================================================================
__global__ __launch_bounds__(256) void k5_node(const float* __restrict__ e,
                                               const float* __restrict__ att,
                                               const float* __restrict__ W_node,
                                               const float* __restrict__ b_node,
                                               float* __restrict__ out_o) {
    const int oc = blockIdx.x, b = blockIdx.y, tid = threadIdx.x;
    const float* w = W_node + (size_t)oc * C1_ * R_;
    const float* eb = e + (size_t)b * R_ * C1_;
    const float* ab = att + b * R_;
    float s = 0.f;
    for (int m = tid; m < C1_ * R_; m += 256) {
        const int c1 = m >> 8, r = m & 255;
        s += w[m] * ab[r] * eb[r * C1_ + c1];
    }
#pragma unroll
    for (int off = 32; off > 0; off >>= 1) s += __shfl_down(s, off, 64);
    __shared__ float red[4];
    if ((tid & 63) == 0) red[tid >> 6] = s;
    __syncthreads();
    if (tid == 0) {
        float tot = red[0] + red[1] + red[2] + red[3] + b_node[oc];
        out_o[b * C2_ + oc] = tot >= 0.f ? tot : 0.01f * tot;
    }
}

extern "C" void kernel_launch(void* const* d_in, const int* in_sizes, int n_in,
                              void* d_out, int out_size, void* d_ws, size_t ws_size,
                              hipStream_t stream) {
    const float* x      = (const float*)d_in[0];
    const float* W_edge = (const float*)d_in[1];
    const float* b_edge = (const float*)d_in[2];
    const float* W1     = (const float*)d_in[3];
    const float* b1     = (const float*)d_in[4];
    const float* W2     = (const float*)d_in[5];
    const float* b2     = (const float*)d_in[6];
    const float* W_node = (const float*)d_in[7];
    const float* b_node = (const float*)d_in[8];
    float* out = (float*)d_out;   // [0,4096): o ; [4096,12288): att

    char* ws = (char*)d_ws;
    unsigned short* y = (unsigned short*)ws;                        // 134217728 B  [B,C,R,T] bf16
    unsigned short* Z = (unsigned short*)(ws + 134217728);          //  33554432 B  [B,C1,C,T] bf16
    float* e_part     = (float*)(ws + 167772160);                   //   4194304 B  [2,B,R,C1] f32
    float* e          = (float*)(ws + 171966464);                   //   2097152 B  [B,R,C1] f32

    k1_normalize<<<dim3(R_, B_), 256, 0, stream>>>(x, y);
    k2_edgeproj<<<dim3(4, C_, B_), 256, 0, stream>>>(W_edge, y, Z);
    k3_edge_gemm<<<dim3(4, B_, 2), 256, 0, stream>>>(y, Z, e_part);
    k3b_combine<<<2048, 256, 0, stream>>>(e_part, b_edge, e);
    k4_att<<<B_, 256, 0, stream>>>(e, W1, b1, W2, b2, out + 4096);
    k5_node<<<dim3(C2_, B_), 256, 0, stream>>>(e, out + 4096, W_node, b_node, out);
}

// Round 2
// 698.376 us; speedup vs baseline: 1.3492x; 1.3492x over previous
//
#include <hip/hip_runtime.h>
#include <hip/hip_bf16.h>

#define B_  32
#define R_  256
#define T_  512
#define C_  16
#define C1_ 64
#define C2_ 128

// ---------- bf16 helpers (store y/Z as raw ushort, RNE rounding) ----------
__device__ __forceinline__ unsigned short f2bf(float f) {
    unsigned u = __float_as_uint(f);
    return (unsigned short)((u + 0x7fffu + ((u >> 16) & 1u)) >> 16);
}
__device__ __forceinline__ float bf2f_lo(unsigned w) { return __uint_as_float(w << 16); }
__device__ __forceinline__ float bf2f_hi(unsigned w) { return __uint_as_float(w & 0xffff0000u); }

// =====================================================================
// K1: x[B,R,T,C] fp32 -> y[B,C,R,T] bf16, rows centered & L2-normalized.
// =====================================================================
__global__ __launch_bounds__(256) void k1_normalize(const float* __restrict__ x,
                                                    unsigned short* __restrict__ y) {
    const int r = blockIdx.x, b = blockIdx.y, tid = threadIdx.x;
    __shared__ float xs[T_ * C_];          // 32 KB
    __shared__ float psum[16][17], psq[16][17];
    __shared__ float s_mean[16], s_inv[16];

    const float4* src = reinterpret_cast<const float4*>(x + ((size_t)(b * R_ + r)) * T_ * C_);
    float4* dst = reinterpret_cast<float4*>(xs);
#pragma unroll
    for (int j = 0; j < 8; ++j) dst[tid + j * 256] = src[tid + j * 256];
    __syncthreads();

    {
        const int c = tid & 15, seg = tid >> 4;
        float s = 0.f, q = 0.f;
#pragma unroll
        for (int i = 0; i < 32; ++i) {
            float v = xs[(seg * 32 + i) * C_ + c];
            s += v; q += v * v;
        }
        psum[seg][c] = s; psq[seg][c] = q;
    }
    __syncthreads();
    if (tid < 16) {
        float S = 0.f, Q = 0.f;
#pragma unroll
        for (int g = 0; g < 16; ++g) { S += psum[g][tid]; Q += psq[g][tid]; }
        float mean = S * (1.f / T_);
        float nrm2 = Q - S * mean;
        s_mean[tid] = mean;
        s_inv[tid] = rsqrtf(nrm2);
    }
    __syncthreads();

    const int cc = tid >> 4, l = tid & 15;
    const float mean = s_mean[cc], inv = s_inv[cc];
    unsigned* out = reinterpret_cast<unsigned*>(y + (((size_t)(b * C_ + cc)) * R_ + r) * T_);
#pragma unroll
    for (int j = 0; j < 16; ++j) {
        const int t = j * 32 + l * 2;
        float v0 = (xs[t * C_ + cc] - mean) * inv;
        float v1 = (xs[(t + 1) * C_ + cc] - mean) * inv;
        out[t >> 1] = (unsigned)f2bf(v0) | ((unsigned)f2bf(v1) << 16);
    }
}

// =====================================================================
// K2: Z[b,o,c,t] = sum_k W_edge[o,c,k] * y[b,c,k,t]   (bf16 out)
// =====================================================================
__global__ __launch_bounds__(256) void k2_edgeproj(const float* __restrict__ W_edge,
                                                   const unsigned short* __restrict__ y,
                                                   unsigned short* __restrict__ Z) {
    const int t0 = blockIdx.x * 128;
    const int c = blockIdx.y;
    const int b = blockIdx.z;
    const int tid = threadIdx.x;

    __shared__ float As[64][36];
    __shared__ float Bs[32][132];

    float acc[4][8];
#pragma unroll
    for (int i = 0; i < 4; ++i)
#pragma unroll
        for (int j = 0; j < 8; ++j) acc[i][j] = 0.f;

    const int ty = tid >> 4, tx = tid & 15;
    const int la_o = tid >> 2, la_k = (tid & 3) * 8;
    const int lb_r = tid >> 3, lb_t = (tid & 7) * 16;

    for (int k0 = 0; k0 < R_; k0 += 32) {
        {
            const float* s = W_edge + ((size_t)(la_o * C_ + c)) * R_ + k0 + la_k;
            float4 a0 = *(const float4*)s;
            float4 a1 = *(const float4*)(s + 4);
            *(float4*)&As[la_o][la_k] = a0;
            *(float4*)&As[la_o][la_k + 4] = a1;
        }
        {
            const unsigned short* s = y + (((size_t)(b * C_ + c)) * R_ + k0 + lb_r) * T_ + t0 + lb_t;
            uint4 p0 = *(const uint4*)s;
            uint4 p1 = *(const uint4*)(s + 8);
            float f[16];
            f[0]=bf2f_lo(p0.x); f[1]=bf2f_hi(p0.x); f[2]=bf2f_lo(p0.y); f[3]=bf2f_hi(p0.y);
            f[4]=bf2f_lo(p0.z); f[5]=bf2f_hi(p0.z); f[6]=bf2f_lo(p0.w); f[7]=bf2f_hi(p0.w);
            f[8]=bf2f_lo(p1.x); f[9]=bf2f_hi(p1.x); f[10]=bf2f_lo(p1.y); f[11]=bf2f_hi(p1.y);
            f[12]=bf2f_lo(p1.z); f[13]=bf2f_hi(p1.z); f[14]=bf2f_lo(p1.w); f[15]=bf2f_hi(p1.w);
#pragma unroll
            for (int q = 0; q < 4; ++q)
                *(float4*)&Bs[lb_r][lb_t + q * 4] = make_float4(f[q*4], f[q*4+1], f[q*4+2], f[q*4+3]);
        }
        __syncthreads();
#pragma unroll
        for (int kk = 0; kk < 32; ++kk) {
            float a0 = As[ty * 4 + 0][kk];
            float a1 = As[ty * 4 + 1][kk];
            float a2 = As[ty * 4 + 2][kk];
            float a3 = As[ty * 4 + 3][kk];
            float4 b0 = *(float4*)&Bs[kk][tx * 8];
            float4 b1 = *(float4*)&Bs[kk][tx * 8 + 4];
            acc[0][0] += a0*b0.x; acc[0][1] += a0*b0.y; acc[0][2] += a0*b0.z; acc[0][3] += a0*b0.w;
            acc[0][4] += a0*b1.x; acc[0][5] += a0*b1.y; acc[0][6] += a0*b1.z; acc[0][7] += a0*b1.w;
            acc[1][0] += a1*b0.x; acc[1][1] += a1*b0.y; acc[1][2] += a1*b0.z; acc[1][3] += a1*b0.w;
            acc[1][4] += a1*b1.x; acc[1][5] += a1*b1.y; acc[1][6] += a1*b1.z; acc[1][7] += a1*b1.w;
            acc[2][0] += a2*b0.x; acc[2][1] += a2*b0.y; acc[2][2] += a2*b0.z; acc[2][3] += a2*b0.w;
            acc[2][4] += a2*b1.x; acc[2][5] += a2*b1.y; acc[2][6] += a2*b1.z; acc[2][7] += a2*b1.w;
            acc[3][0] += a3*b0.x; acc[3][1] += a3*b0.y; acc[3][2] += a3*b0.z; acc[3][3] += a3*b0.w;
            acc[3][4] += a3*b1.x; acc[3][5] += a3*b1.y; acc[3][6] += a3*b1.z; acc[3][7] += a3*b1.w;
        }
        __syncthreads();
    }

#pragma unroll
    for (int i = 0; i < 4; ++i) {
        const int o = ty * 4 + i;
        unsigned short* d = Z + (((size_t)(b * C1_ + o)) * C_ + c) * T_ + t0 + tx * 8;
        uint4 pk;
        pk.x = (unsigned)f2bf(acc[i][0]) | ((unsigned)f2bf(acc[i][1]) << 16);
        pk.y = (unsigned)f2bf(acc[i][2]) | ((unsigned)f2bf(acc[i][3]) << 16);
        pk.z = (unsigned)f2bf(acc[i][4]) | ((unsigned)f2bf(acc[i][5]) << 16);
        pk.w = (unsigned)f2bf(acc[i][6]) | ((unsigned)f2bf(acc[i][7]) << 16);
        *(uint4*)d = pk;
    }
}

// =====================================================================
// K3: e_part[half,b,o,r] = sum_{c in half} sum_t y[b,c,r,t]*Z[b,o,c,t]
// NOTE: output now o-major (transposed) to feed k5 in W_node's k-order.
// =====================================================================
__global__ __launch_bounds__(256) void k3_edge_gemm(const unsigned short* __restrict__ y,
                                                    const unsigned short* __restrict__ Z,
                                                    float* __restrict__ e_part) {
    const int r0 = blockIdx.x * 64;
    const int b = blockIdx.y;
    const int half = blockIdx.z;
    const int c0 = half * 8;
    const int tid = threadIdx.x;

    __shared__ float Ys[64][68];   // [tt][rr]
    __shared__ float Zs[64][68];   // [tt][oo]

    float acc[4][4];
#pragma unroll
    for (int i = 0; i < 4; ++i)
#pragma unroll
        for (int j = 0; j < 4; ++j) acc[i][j] = 0.f;

    const int ty = tid >> 4, tx = tid & 15;     // r = r0+ty*4+i, o = tx*4+j
    const int lrow = tid >> 2;
    const int lt = (tid & 3) * 16;

    for (int ci = 0; ci < 8; ++ci) {
        const int c = c0 + ci;
        const unsigned short* yb = y + (((size_t)(b * C_ + c)) * R_ + r0 + lrow) * T_;
        const unsigned short* zb = Z + (((size_t)(b * C1_ + lrow)) * C_ + c) * T_;
        for (int tc = 0; tc < 8; ++tc) {
            const int t0 = tc * 64;
            uint4 ya = *(const uint4*)(yb + t0 + lt);
            uint4 yc = *(const uint4*)(yb + t0 + lt + 8);
            uint4 za = *(const uint4*)(zb + t0 + lt);
            uint4 zc = *(const uint4*)(zb + t0 + lt + 8);
            __syncthreads();
            float f[16];
            f[0]=bf2f_lo(ya.x); f[1]=bf2f_hi(ya.x); f[2]=bf2f_lo(ya.y); f[3]=bf2f_hi(ya.y);
            f[4]=bf2f_lo(ya.z); f[5]=bf2f_hi(ya.z); f[6]=bf2f_lo(ya.w); f[7]=bf2f_hi(ya.w);
            f[8]=bf2f_lo(yc.x); f[9]=bf2f_hi(yc.x); f[10]=bf2f_lo(yc.y); f[11]=bf2f_hi(yc.y);
            f[12]=bf2f_lo(yc.z); f[13]=bf2f_hi(yc.z); f[14]=bf2f_lo(yc.w); f[15]=bf2f_hi(yc.w);
#pragma unroll
            for (int i = 0; i < 16; ++i) Ys[lt + i][lrow] = f[i];
            f[0]=bf2f_lo(za.x); f[1]=bf2f_hi(za.x); f[2]=bf2f_lo(za.y); f[3]=bf2f_hi(za.y);
            f[4]=bf2f_lo(za.z); f[5]=bf2f_hi(za.z); f[6]=bf2f_lo(za.w); f[7]=bf2f_hi(za.w);
            f[8]=bf2f_lo(zc.x); f[9]=bf2f_hi(zc.x); f[10]=bf2f_lo(zc.y); f[11]=bf2f_hi(zc.y);
            f[12]=bf2f_lo(zc.z); f[13]=bf2f_hi(zc.z); f[14]=bf2f_lo(zc.w); f[15]=bf2f_hi(zc.w);
#pragma unroll
            for (int i = 0; i < 16; ++i) Zs[lt + i][lrow] = f[i];
            __syncthreads();
#pragma unroll
            for (int tt = 0; tt < 64; ++tt) {
                float4 yv = *(float4*)&Ys[tt][ty * 4];
                float4 zv = *(float4*)&Zs[tt][tx * 4];
                acc[0][0] += yv.x*zv.x; acc[0][1] += yv.x*zv.y; acc[0][2] += yv.x*zv.z; acc[0][3] += yv.x*zv.w;
                acc[1][0] += yv.y*zv.x; acc[1][1] += yv.y*zv.y; acc[1][2] += yv.y*zv.z; acc[1][3] += yv.y*zv.w;
                acc[2][0] += yv.z*zv.x; acc[2][1] += yv.z*zv.y; acc[2][2] += yv.z*zv.z; acc[2][3] += yv.z*zv.w;
                acc[3][0] += yv.w*zv.x; acc[3][1] += yv.w*zv.y; acc[3][2] += yv.w*zv.z; acc[3][3] += yv.w*zv.w;
            }
        }
    }
    // store transposed: e_part[half][b][o][r], float4 along r (i-dim)
#pragma unroll
    for (int j = 0; j < 4; ++j) {
        const int o = tx * 4 + j;
        float* d = e_part + (((size_t)((half * B_ + b) * C1_) + o) * R_) + r0 + ty * 4;
        *(float4*)d = make_float4(acc[0][j], acc[1][j], acc[2][j], acc[3][j]);
    }
}

// K3b: eT[b,o,r] = leaky_relu(part0 + part1 + b_edge[o])   (o-major layout)
__global__ __launch_bounds__(256) void k3b_combine(const float* __restrict__ e_part,
                                                   const float* __restrict__ b_edge,
                                                   float* __restrict__ eT) {
    const int idx = blockIdx.x * 256 + threadIdx.x;   // (b*64+o)*256 + r
    float v = e_part[idx] + e_part[B_ * R_ * C1_ + idx] + b_edge[(idx >> 8) & 63];
    eT[idx] = v >= 0.f ? v : 0.01f * v;
}

// =====================================================================
// K4: attention MLP (reads eT[b,o,r]). One block per b.
// =====================================================================
__global__ __launch_bounds__(256) void k4_att(const float* __restrict__ eT,
                                              const float* __restrict__ W1, const float* __restrict__ b1,
                                              const float* __restrict__ W2, const float* __restrict__ b2,
                                              float* __restrict__ out_att) {
    const int b = blockIdx.x, tid = threadIdx.x;
    __shared__ float pooled[R_];
    __shared__ float h[64];
    {
        const float* eb = eT + (size_t)b * C1_ * R_;
        float s = 0.f;
#pragma unroll
        for (int o = 0; o < C1_; ++o) s += eb[o * R_ + tid];   // coalesced over tid=r
        pooled[tid] = s * (1.f / 64.f);
    }
    __syncthreads();
    if (tid < 64) {
        float a = b1[tid];
        const float* w = W1 + tid * R_;
        for (int r = 0; r < R_; ++r) a += w[r] * pooled[r];
        h[tid] = fmaxf(a, 0.f);
    }
    __syncthreads();
    {
        float a = b2[tid];
        const float* w = W2 + tid * 64;
#pragma unroll
        for (int j = 0; j < 64; ++j) a += w[j] * h[j];
        out_att[b * R_ + tid] = 1.f / (1.f + __expf(-a));
    }
}

// =====================================================================
// K5a: K-split GEMM. Block kc owns K-chunk [kc*64, kc*64+64) of k=c1*256+r.
// partial[kc][b][oc] = sum_kk att[b,r]*eT[b,k] * W_node[oc,k]
// LDS rows stride 17 float4s => column b128 reads cycle all bank-quads.
// =====================================================================
__global__ __launch_bounds__(256) void k5_gemm(const float* __restrict__ eT,
                                               const float* __restrict__ att,
                                               const float* __restrict__ W_node,
                                               float* __restrict__ partial) {
    const int kc = blockIdx.x;          // 0..255
    const int k0 = kc * 64;
    const int r0 = k0 & 255;
    const int tid = threadIdx.x;

    __shared__ __align__(16) float gs[32 * 68];    // [b][17 float4]
    __shared__ __align__(16) float Ws[128 * 68];   // [oc][17 float4]
    float4* gs4 = reinterpret_cast<float4*>(gs);
    float4* Ws4 = reinterpret_cast<float4*>(Ws);

    // stage g = att * eT  (32 rows x 64 floats)
    {
        const int b = tid >> 3;
        const float4* ebase = reinterpret_cast<const float4*>(eT) + (size_t)b * 4096 + (k0 >> 2);
        const float4* abase = reinterpret_cast<const float4*>(att + b * R_ + r0);
#pragma unroll
        for (int j = 0; j < 2; ++j) {
            const int kk4 = (tid & 7) + j * 8;
            float4 v = ebase[kk4];
            float4 a = abase[kk4];
            v.x *= a.x; v.y *= a.y; v.z *= a.z; v.w *= a.w;
            gs4[b * 17 + kk4] = v;
        }
    }
    // stage W_node chunk (128 rows x 64 floats)
    {
        const float4* wbase = reinterpret_cast<const float4*>(W_node) + (k0 >> 2);
#pragma unroll
        for (int j = 0; j < 8; ++j) {
            const int i = j * 256 + tid;
            const int oc = i >> 4, col4 = i & 15;
            Ws4[oc * 17 + col4] = wbase[(size_t)oc * 4096 + col4];
        }
    }
    __syncthreads();

    const int tx = tid & 31, ty = tid >> 5;   // b = ty+8i, oc = tx+32j
    float acc[4][4];
#pragma unroll
    for (int i = 0; i < 4; ++i)
#pragma unroll
        for (int j = 0; j < 4; ++j) acc[i][j] = 0.f;

#pragma unroll
    for (int kk4 = 0; kk4 < 16; ++kk4) {
        float4 g4[4], w4[4];
#pragma unroll
        for (int i = 0; i < 4; ++i) g4[i] = gs4[(ty + 8 * i) * 17 + kk4];
#pragma unroll
        for (int j = 0; j < 4; ++j) w4[j] = Ws4[(tx + 32 * j) * 17 + kk4];
#pragma unroll
        for (int i = 0; i < 4; ++i)
#pragma unroll
            for (int j = 0; j < 4; ++j)
                acc[i][j] += g4[i].x * w4[j].x + g4[i].y * w4[j].y
                           + g4[i].z * w4[j].z + g4[i].w * w4[j].w;
    }

    float* d = partial + (size_t)kc * (B_ * C2_);
#pragma unroll
    for (int i = 0; i < 4; ++i)
#pragma unroll
        for (int j = 0; j < 4; ++j)
            d[(ty + 8 * i) * C2_ + tx + 32 * j] = acc[i][j];
}

// K5b: out[b,oc] = leaky(sum_kc partial[kc][b][oc] + b_node[oc])
__global__ __launch_bounds__(256) void k5_reduce(const float* __restrict__ partial,
                                                 const float* __restrict__ b_node,
                                                 float* __restrict__ out_o) {
    const int idx = blockIdx.x * 256 + threadIdx.x;   // < 4096
    float s = 0.f;
    for (int kc = 0; kc < 256; ++kc) s += partial[(size_t)kc * (B_ * C2_) + idx];
    s += b_node[idx & 127];
    out_o[idx] = s >= 0.f ? s : 0.01f * s;
}

extern "C" void kernel_launch(void* const* d_in, const int* in_sizes, int n_in,
                              void* d_out, int out_size, void* d_ws, size_t ws_size,
                              hipStream_t stream) {
    const float* x      = (const float*)d_in[0];
    const float* W_edge = (const float*)d_in[1];
    const float* b_edge = (const float*)d_in[2];
    const float* W1     = (const float*)d_in[3];
    const float* b1     = (const float*)d_in[4];
    const float* W2     = (const float*)d_in[5];
    const float* b2     = (const float*)d_in[6];
    const float* W_node = (const float*)d_in[7];
    const float* b_node = (const float*)d_in[8];
    float* out = (float*)d_out;   // [0,4096): o ; [4096,12288): att

    char* ws = (char*)d_ws;
    unsigned short* y = (unsigned short*)ws;                 // 134217728 B  [B,C,R,T] bf16
    unsigned short* Z = (unsigned short*)(ws + 134217728);   //  33554432 B  [B,C1,C,T] bf16
    float* e_part     = (float*)(ws + 167772160);            //   4194304 B  [2,B,C1,R] f32 (reused as partial)
    float* partial    = e_part;                              //   4194304 B  [256,B,C2] f32 (after k3b)
    float* eT         = (float*)(ws + 171966464);            //   2097152 B  [B,C1,R] f32

    k1_normalize<<<dim3(R_, B_), 256, 0, stream>>>(x, y);
    k2_edgeproj<<<dim3(4, C_, B_), 256, 0, stream>>>(W_edge, y, Z);
    k3_edge_gemm<<<dim3(4, B_, 2), 256, 0, stream>>>(y, Z, e_part);
    k3b_combine<<<2048, 256, 0, stream>>>(e_part, b_edge, eT);
    k4_att<<<B_, 256, 0, stream>>>(eT, W1, b1, W2, b2, out + 4096);
    k5_gemm<<<256, 256, 0, stream>>>(eT, out + 4096, W_node, partial);
    k5_reduce<<<16, 256, 0, stream>>>(partial, b_node, out);
}

// Round 3
// 569.590 us; speedup vs baseline: 1.6543x; 1.2261x over previous
//
#include <hip/hip_runtime.h>
#include <hip/hip_bf16.h>

#define B_  32
#define R_  256
#define T_  512
#define C_  16
#define C1_ 64
#define C2_ 128

typedef short short8 __attribute__((ext_vector_type(8)));   // 8 bf16 = 4 VGPRs (MFMA A/B frag)
typedef float f32x4  __attribute__((ext_vector_type(4)));   // MFMA C/D frag

// ---------- bf16 helpers (RNE rounding) ----------
__device__ __forceinline__ unsigned short f2bf(float f) {
    unsigned u = __float_as_uint(f);
    return (unsigned short)((u + 0x7fffu + ((u >> 16) & 1u)) >> 16);
}

// =====================================================================
// K0: W_edge fp32 [o][c][r] -> Wb bf16 (same flat order), one-time cvt.
// =====================================================================
__global__ __launch_bounds__(256) void k0_wcvt(const float* __restrict__ W,
                                               unsigned short* __restrict__ Wb) {
    const int i = (blockIdx.x * 256 + threadIdx.x) * 4;   // 262144 total
    float4 v = *(const float4*)(W + i);
    uint2 pk;
    pk.x = (unsigned)f2bf(v.x) | ((unsigned)f2bf(v.y) << 16);
    pk.y = (unsigned)f2bf(v.z) | ((unsigned)f2bf(v.w) << 16);
    *(uint2*)(Wb + i) = pk;
}

// =====================================================================
// K1: x[B,R,T,C] fp32 -> y[B,C,R,T] bf16, rows centered & L2-normalized.
// =====================================================================
__global__ __launch_bounds__(256) void k1_normalize(const float* __restrict__ x,
                                                    unsigned short* __restrict__ y) {
    const int r = blockIdx.x, b = blockIdx.y, tid = threadIdx.x;
    __shared__ float xs[T_ * C_];          // 32 KB
    __shared__ float psum[16][17], psq[16][17];
    __shared__ float s_mean[16], s_inv[16];

    const float4* src = reinterpret_cast<const float4*>(x + ((size_t)(b * R_ + r)) * T_ * C_);
    float4* dst = reinterpret_cast<float4*>(xs);
#pragma unroll
    for (int j = 0; j < 8; ++j) dst[tid + j * 256] = src[tid + j * 256];
    __syncthreads();

    {
        const int c = tid & 15, seg = tid >> 4;
        float s = 0.f, q = 0.f;
#pragma unroll
        for (int i = 0; i < 32; ++i) {
            float v = xs[(seg * 32 + i) * C_ + c];
            s += v; q += v * v;
        }
        psum[seg][c] = s; psq[seg][c] = q;
    }
    __syncthreads();
    if (tid < 16) {
        float S = 0.f, Q = 0.f;
#pragma unroll
        for (int g = 0; g < 16; ++g) { S += psum[g][tid]; Q += psq[g][tid]; }
        float mean = S * (1.f / T_);
        float nrm2 = Q - S * mean;
        s_mean[tid] = mean;
        s_inv[tid] = rsqrtf(nrm2);
    }
    __syncthreads();

    const int cc = tid >> 4, l = tid & 15;
    const float mean = s_mean[cc], inv = s_inv[cc];
    unsigned* out = reinterpret_cast<unsigned*>(y + (((size_t)(b * C_ + cc)) * R_ + r) * T_);
#pragma unroll
    for (int j = 0; j < 16; ++j) {
        const int t = j * 32 + l * 2;
        float v0 = (xs[t * C_ + cc] - mean) * inv;
        float v1 = (xs[(t + 1) * C_ + cc] - mean) * inv;
        out[t >> 1] = (unsigned)f2bf(v0) | ((unsigned)f2bf(v1) << 16);
    }
}

// =====================================================================
// K1t: y[b,c,r,t] -> yT[b,c,t,r]  (bf16 transpose, register repack,
// no LDS). Thread: 8 rows x 4 t per iter; emits 4 t-rows x 8-r uint4.
// =====================================================================
__global__ __launch_bounds__(256) void k1t_transpose(const unsigned short* __restrict__ y,
                                                     unsigned short* __restrict__ yT) {
    const int c = blockIdx.x, b = blockIdx.y;
    const unsigned short* src = y + ((size_t)(b * C_ + c)) * R_ * T_;
    unsigned short* dstp = yT + ((size_t)(b * C_ + c)) * T_ * R_;
    const int tg = threadIdx.x & 7;          // t-group
    const int r0 = (threadIdx.x >> 3) * 8;   // 8-row strip
#pragma unroll 4
    for (int it = 0; it < 16; ++it) {
        const int t0 = (tg + 8 * it) * 4;
        uint2 u[8];
#pragma unroll
        for (int k = 0; k < 8; ++k)
            u[k] = *(const uint2*)(src + (size_t)(r0 + k) * T_ + t0);
#pragma unroll
        for (int j = 0; j < 4; ++j) {
            unsigned e[8];
#pragma unroll
            for (int k = 0; k < 8; ++k) {
                unsigned comp = (j < 2) ? u[k].x : u[k].y;
                e[k] = (j & 1) ? (comp >> 16) : (comp & 0xffffu);
            }
            uint4 o4;
            o4.x = e[0] | (e[1] << 16);
            o4.y = e[2] | (e[3] << 16);
            o4.z = e[4] | (e[5] << 16);
            o4.w = e[6] | (e[7] << 16);
            *(uint4*)(dstp + (size_t)(t0 + j) * R_ + r0) = o4;
        }
    }
}

// =====================================================================
// K2 (MFMA): per (t-half, c, b): Zt[t][o] = sum_r yT[t][r] * W[o][r].
// M=256(t), N=64(o), K=256(r). Wave: 64-t strip, 4x4 16x16 tiles.
// A-frag: yT (r-contig, 16B/lane); B-frag: Wb (r-contig, 16B/lane).
// Output Z[b][o][c][t] bf16 (t-contig) via 8B packed stores.
// =====================================================================
__global__ __launch_bounds__(256) void k2_mfma(const unsigned short* __restrict__ yT,
                                               const unsigned short* __restrict__ Wb,
                                               unsigned short* __restrict__ Z) {
    const int th = blockIdx.x, c = blockIdx.y, b = blockIdx.z;
    const int tid = threadIdx.x;
    const int w = tid >> 6, l = tid & 63;
    const int lm = l & 15, lk = (l >> 4) * 8;

    const unsigned short* ab = yT + ((size_t)(b * C_ + c)) * T_ * R_;   // [t][r]
    const unsigned short* wb = Wb + (size_t)c * R_;                     // + o*C_*R_
    const int tbase = th * 256 + w * 64;

    f32x4 acc[4][4];
#pragma unroll
    for (int i = 0; i < 4; ++i)
#pragma unroll
        for (int j = 0; j < 4; ++j) acc[i][j] = (f32x4){0.f, 0.f, 0.f, 0.f};

    for (int r0 = 0; r0 < R_; r0 += 32) {
        short8 A[4], Bf[4];
#pragma unroll
        for (int mt = 0; mt < 4; ++mt)
            A[mt] = *(const short8*)(ab + (size_t)(tbase + mt * 16 + lm) * R_ + r0 + lk);
#pragma unroll
        for (int nt = 0; nt < 4; ++nt)
            Bf[nt] = *(const short8*)(wb + (size_t)(nt * 16 + lm) * (C_ * R_) + r0 + lk);
#pragma unroll
        for (int mt = 0; mt < 4; ++mt)
#pragma unroll
            for (int nt = 0; nt < 4; ++nt)
                acc[mt][nt] = __builtin_amdgcn_mfma_f32_16x16x32_bf16(A[mt], Bf[nt], acc[mt][nt], 0, 0, 0);
    }

    const int rowb = (l >> 4) * 4;
#pragma unroll
    for (int mt = 0; mt < 4; ++mt) {
#pragma unroll
        for (int nt = 0; nt < 4; ++nt) {
            const int o = nt * 16 + lm;
            const int tb = tbase + mt * 16 + rowb;
            uint2 pk;
            pk.x = (unsigned)f2bf(acc[mt][nt][0]) | ((unsigned)f2bf(acc[mt][nt][1]) << 16);
            pk.y = (unsigned)f2bf(acc[mt][nt][2]) | ((unsigned)f2bf(acc[mt][nt][3]) << 16);
            *(uint2*)(Z + (((size_t)b * C1_ + o) * C_ + c) * T_ + tb) = pk;
        }
    }
}

// =====================================================================
// K3 (MFMA): per (c, b): partial[c][b][o][r] = sum_t y[b,c,r,t]*Z[b,o,c,t]
// M=256(r), N=64(o), K=512(t). Wave: 64-r strip, 4x4 16x16 tiles.
// Both frags t-contiguous -> direct 16B global loads, no LDS.
// =====================================================================
__global__ __launch_bounds__(256) void k3_mfma(const unsigned short* __restrict__ y,
                                               const unsigned short* __restrict__ Z,
                                               float* __restrict__ partial) {
    const int c = blockIdx.x, b = blockIdx.y;
    const int tid = threadIdx.x;
    const int w = tid >> 6, l = tid & 63;
    const int lm = l & 15, lk = (l >> 4) * 8;

    const unsigned short* yb = y + ((size_t)(b * C_ + c)) * R_ * T_;        // [r][t]
    const unsigned short* zb = Z + ((size_t)b * C1_ * C_ + c) * T_;         // + o*C_*T_

    f32x4 acc[4][4];
#pragma unroll
    for (int i = 0; i < 4; ++i)
#pragma unroll
        for (int j = 0; j < 4; ++j) acc[i][j] = (f32x4){0.f, 0.f, 0.f, 0.f};

    for (int t0 = 0; t0 < T_; t0 += 32) {
        short8 A[4], Bf[4];
#pragma unroll
        for (int mt = 0; mt < 4; ++mt)
            A[mt] = *(const short8*)(yb + (size_t)(w * 64 + mt * 16 + lm) * T_ + t0 + lk);
#pragma unroll
        for (int nt = 0; nt < 4; ++nt)
            Bf[nt] = *(const short8*)(zb + (size_t)(nt * 16 + lm) * (C_ * T_) + t0 + lk);
#pragma unroll
        for (int mt = 0; mt < 4; ++mt)
#pragma unroll
            for (int nt = 0; nt < 4; ++nt)
                acc[mt][nt] = __builtin_amdgcn_mfma_f32_16x16x32_bf16(A[mt], Bf[nt], acc[mt][nt], 0, 0, 0);
    }

    const int rowb = (l >> 4) * 4;
#pragma unroll
    for (int mt = 0; mt < 4; ++mt) {
#pragma unroll
        for (int nt = 0; nt < 4; ++nt) {
            const int o = nt * 16 + lm;
            const int rb = w * 64 + mt * 16 + rowb;
            float* d = partial + (((size_t)c * B_ + b) * C1_ + o) * R_ + rb;
            *(float4*)d = make_float4(acc[mt][nt][0], acc[mt][nt][1], acc[mt][nt][2], acc[mt][nt][3]);
        }
    }
}

// K3b: eT[b,o,r] = leaky_relu(sum_c partial[c][b][o][r] + b_edge[o])
__global__ __launch_bounds__(256) void k3b_combine(const float* __restrict__ partial,
                                                   const float* __restrict__ b_edge,
                                                   float* __restrict__ eT) {
    const int idx4 = blockIdx.x * 256 + threadIdx.x;   // 0..131071 (float4 index)
    const float4* p = (const float4*)partial;
    float4 s = p[idx4];
#pragma unroll
    for (int c = 1; c < C_; ++c) {
        float4 v = p[(size_t)c * 131072 + idx4];
        s.x += v.x; s.y += v.y; s.z += v.z; s.w += v.w;
    }
    const float bo = b_edge[(idx4 >> 6) & 63];
    s.x += bo; s.y += bo; s.z += bo; s.w += bo;
    s.x = s.x >= 0.f ? s.x : 0.01f * s.x;
    s.y = s.y >= 0.f ? s.y : 0.01f * s.y;
    s.z = s.z >= 0.f ? s.z : 0.01f * s.z;
    s.w = s.w >= 0.f ? s.w : 0.01f * s.w;
    ((float4*)eT)[idx4] = s;
}

// =====================================================================
// K4: attention MLP (reads eT[b,o,r]). One block per b.
// =====================================================================
__global__ __launch_bounds__(256) void k4_att(const float* __restrict__ eT,
                                              const float* __restrict__ W1, const float* __restrict__ b1,
                                              const float* __restrict__ W2, const float* __restrict__ b2,
                                              float* __restrict__ out_att) {
    const int b = blockIdx.x, tid = threadIdx.x;
    __shared__ float pooled[R_];
    __shared__ float h[64];
    {
        const float* eb = eT + (size_t)b * C1_ * R_;
        float s = 0.f;
#pragma unroll
        for (int o = 0; o < C1_; ++o) s += eb[o * R_ + tid];
        pooled[tid] = s * (1.f / 64.f);
    }
    __syncthreads();
    if (tid < 64) {
        float a = b1[tid];
        const float* w = W1 + tid * R_;
        for (int r = 0; r < R_; ++r) a += w[r] * pooled[r];
        h[tid] = fmaxf(a, 0.f);
    }
    __syncthreads();
    {
        float a = b2[tid];
        const float* w = W2 + tid * 64;
#pragma unroll
        for (int j = 0; j < 64; ++j) a += w[j] * h[j];
        out_att[b * R_ + tid] = 1.f / (1.f + __expf(-a));
    }
}

// =====================================================================
// K5a: K-split GEMM over k=c1*256+r; block kc owns 64-wide K-chunk.
// =====================================================================
__global__ __launch_bounds__(256) void k5_gemm(const float* __restrict__ eT,
                                               const float* __restrict__ att,
                                               const float* __restrict__ W_node,
                                               float* __restrict__ partial) {
    const int kc = blockIdx.x;          // 0..255
    const int k0 = kc * 64;
    const int r0 = k0 & 255;
    const int tid = threadIdx.x;

    __shared__ __align__(16) float gs[32 * 68];    // [b][17 float4]
    __shared__ __align__(16) float Ws[128 * 68];   // [oc][17 float4]
    float4* gs4 = reinterpret_cast<float4*>(gs);
    float4* Ws4 = reinterpret_cast<float4*>(Ws);

    {
        const int b = tid >> 3;
        const float4* ebase = reinterpret_cast<const float4*>(eT) + (size_t)b * 4096 + (k0 >> 2);
        const float4* abase = reinterpret_cast<const float4*>(att + b * R_ + r0);
#pragma unroll
        for (int j = 0; j < 2; ++j) {
            const int kk4 = (tid & 7) + j * 8;
            float4 v = ebase[kk4];
            float4 a = abase[kk4];
            v.x *= a.x; v.y *= a.y; v.z *= a.z; v.w *= a.w;
            gs4[b * 17 + kk4] = v;
        }
    }
    {
        const float4* wbase = reinterpret_cast<const float4*>(W_node) + (k0 >> 2);
#pragma unroll
        for (int j = 0; j < 8; ++j) {
            const int i = j * 256 + tid;
            const int oc = i >> 4, col4 = i & 15;
            Ws4[oc * 17 + col4] = wbase[(size_t)oc * 4096 + col4];
        }
    }
    __syncthreads();

    const int tx = tid & 31, ty = tid >> 5;
    float acc[4][4];
#pragma unroll
    for (int i = 0; i < 4; ++i)
#pragma unroll
        for (int j = 0; j < 4; ++j) acc[i][j] = 0.f;

#pragma unroll
    for (int kk4 = 0; kk4 < 16; ++kk4) {
        float4 g4[4], w4[4];
#pragma unroll
        for (int i = 0; i < 4; ++i) g4[i] = gs4[(ty + 8 * i) * 17 + kk4];
#pragma unroll
        for (int j = 0; j < 4; ++j) w4[j] = Ws4[(tx + 32 * j) * 17 + kk4];
#pragma unroll
        for (int i = 0; i < 4; ++i)
#pragma unroll
            for (int j = 0; j < 4; ++j)
                acc[i][j] += g4[i].x * w4[j].x + g4[i].y * w4[j].y
                           + g4[i].z * w4[j].z + g4[i].w * w4[j].w;
    }

    float* d = partial + (size_t)kc * (B_ * C2_);
#pragma unroll
    for (int i = 0; i < 4; ++i)
#pragma unroll
        for (int j = 0; j < 4; ++j)
            d[(ty + 8 * i) * C2_ + tx + 32 * j] = acc[i][j];
}

// K5b: out[b,oc] = leaky(sum_kc partial[kc][b][oc] + b_node[oc])
__global__ __launch_bounds__(256) void k5_reduce(const float* __restrict__ partial,
                                                 const float* __restrict__ b_node,
                                                 float* __restrict__ out_o) {
    const int idx = blockIdx.x * 256 + threadIdx.x;   // < 4096
    float s = 0.f;
    for (int kc = 0; kc < 256; ++kc) s += partial[(size_t)kc * (B_ * C2_) + idx];
    s += b_node[idx & 127];
    out_o[idx] = s >= 0.f ? s : 0.01f * s;
}

extern "C" void kernel_launch(void* const* d_in, const int* in_sizes, int n_in,
                              void* d_out, int out_size, void* d_ws, size_t ws_size,
                              hipStream_t stream) {
    const float* x      = (const float*)d_in[0];
    const float* W_edge = (const float*)d_in[1];
    const float* b_edge = (const float*)d_in[2];
    const float* W1     = (const float*)d_in[3];
    const float* b1     = (const float*)d_in[4];
    const float* W2     = (const float*)d_in[5];
    const float* b2     = (const float*)d_in[6];
    const float* W_node = (const float*)d_in[7];
    const float* b_node = (const float*)d_in[8];
    float* out = (float*)d_out;   // [0,4096): o ; [4096,12288): att

    char* ws = (char*)d_ws;
    unsigned short* y  = (unsigned short*)ws;                 // 134217728 B [B,C,R,T] bf16
    unsigned short* yT = (unsigned short*)(ws + 134217728);   // 134217728 B [B,C,T,R] bf16
    float* partial3    = (float*)(ws + 134217728);            // aliases yT: [C][B][C1][R] f32 (33.5MB, after k2)
    unsigned short* Z  = (unsigned short*)(ws + 268435456);   //  33554432 B [B,C1,C,T] bf16
    unsigned short* Wb = (unsigned short*)(ws + 301989888);   //    524288 B [C1,C,R] bf16
    float* eT          = (float*)(ws + 302514176);            //   2097152 B [B,C1,R] f32
    float* partial5    = (float*)(ws + 304611328);            //   4194304 B [256,B,C2] f32

    k0_wcvt<<<256, 256, 0, stream>>>(W_edge, Wb);
    k1_normalize<<<dim3(R_, B_), 256, 0, stream>>>(x, y);
    k1t_transpose<<<dim3(C_, B_), 256, 0, stream>>>(y, yT);
    k2_mfma<<<dim3(2, C_, B_), 256, 0, stream>>>(yT, Wb, Z);
    k3_mfma<<<dim3(C_, B_), 256, 0, stream>>>(y, Z, partial3);
    k3b_combine<<<512, 256, 0, stream>>>(partial3, b_edge, eT);
    k4_att<<<B_, 256, 0, stream>>>(eT, W1, b1, W2, b2, out + 4096);
    k5_gemm<<<256, 256, 0, stream>>>(eT, out + 4096, W_node, partial5);
    k5_reduce<<<16, 256, 0, stream>>>(partial5, b_node, out);
}